// Round 1
// baseline (251.555 us; speedup 1.0000x reference)
//
#include <hip/hip_runtime.h>
#include <stdint.h>

// ChessMultiStageAttention: B=4096 fused blocks of (pos-add, LN, QKV, 8-head
// attention S=64 D=8 with chess bias, out-proj, residual). f32 I/O, bf16 MFMA
// (16x16x32_bf16) with f32 accum.
//
// Round-6: P2 eliminated -> LDS 53248->34816 B -> 4 WG/CU (was 3).
//  * x_norm written in-place into P1 rows (bf16 cols 0..63 of the 272-B row);
//    f32 LN stats kept. sched_barrier(0) pins read-before-overwrite.
//  * Stage-E heads reassigned {w,w+4} -> {2w,2w+1}: Q/K/V all wave-local.
//    V^T stays in registers (packed bf16 pairs), transposed to PV A-frags via
//    8 shuffles + 4 selects per (item,kf). Barrier #3 removed (same-wave LDS
//    ordering suffices for Q/K).
//
// MFMA layouts (m89-verified):
//   A: lane m=lane&15 holds row m, k=(lane>>4)*8+j (k-contiguous 16B)
//   B: lane holds col n=lane&15, k=(lane>>4)*8+j
//   C/D: col=lane&15, row=(lane>>4)*4+reg
//
// LDS per item (17408 B; x2 = 34816 B -> 4 WG/CU):
//   P1 [64][136] bf16: (A-B) f32 x+pos view [64][68] / (C) x_norm bf16 in-place
//       cols 0..63 / (D) Q cols 0..63, K cols 64..127 (overwrite after XF load)
//       / (E) AO overwrites own heads' K cols (wave-private)

typedef __attribute__((ext_vector_type(8))) __bf16 bfrag;
typedef __attribute__((ext_vector_type(4))) __bf16 bf4;
typedef __attribute__((ext_vector_type(4))) float f32x4;
typedef __attribute__((ext_vector_type(4))) uint32_t u32x4;

#define MFMA16(a, b, c) __builtin_amdgcn_mfma_f32_16x16x32_bf16((a), (b), (c), 0, 0, 0)

static __device__ __forceinline__ bfrag bsplat(float v) {
  bfrag z;
#pragma unroll
  for (int i = 0; i < 8; i++) z[i] = (__bf16)v;
  return z;
}

static __device__ __forceinline__ bfrag cvt8(const float* __restrict__ p) {
  float4 a = *(const float4*)p, b = *(const float4*)(p + 4);
  bfrag r;
  r[0] = (__bf16)a.x; r[1] = (__bf16)a.y; r[2] = (__bf16)a.z; r[3] = (__bf16)a.w;
  r[4] = (__bf16)b.x; r[5] = (__bf16)b.y; r[6] = (__bf16)b.z; r[7] = (__bf16)b.w;
  return r;
}

static __device__ __forceinline__ uint32_t pack2(float a, float b) {
  unsigned short ua = __builtin_bit_cast(unsigned short, (__bf16)a);
  unsigned short ub = __builtin_bit_cast(unsigned short, (__bf16)b);
  return (uint32_t)ua | ((uint32_t)ub << 16);
}

__global__ __launch_bounds__(256, 4) void chess_attn_kernel(
    const float* __restrict__ xg,    const float* __restrict__ posg,
    const float* __restrict__ gam,   const float* __restrict__ bet,
    const float* __restrict__ qkvw,  const float* __restrict__ qkvb,
    const float* __restrict__ outw,  const float* __restrict__ outb,
    const float* __restrict__ biasg, float* __restrict__ outg) {
  __shared__ __attribute__((aligned(16))) __bf16 P1[2][64 * 136];  // 2x17408 B

  const int tid = threadIdx.x, lane = tid & 63, w = tid >> 6;
  const int m = lane & 15, g = lane >> 4;
  const int b0 = blockIdx.x * 2;
  const float LN2I = 1.4426950408889634f;            // log2(e)
  const float SCL2 = 0.35355339059327373f * LN2I;    // (1/sqrt(8))*log2(e)

  // ---- A: x + pos -> P1[it] as f32 [64][68]; wave w fills rows 16w..16w+15 ----
  {
    const float4* pp = (const float4*)(posg + (size_t)lane * 64 + w * 16);
    float4 pv[4] = {pp[0], pp[1], pp[2], pp[3]};     // shared across items
#pragma unroll
    for (int it = 0; it < 2; it++) {
      float* XP = (float*)P1[it];
      const float4* px = (const float4*)(xg + ((size_t)(b0 + it) * 64 + lane) * 64 + w * 16);
#pragma unroll
      for (int v = 0; v < 4; v++) {
        float4 xv = px[v];
        const int s = w * 16 + v * 4;
        XP[(s + 0) * 68 + lane] = xv.x + pv[v].x;
        XP[(s + 1) * 68 + lane] = xv.y + pv[v].y;
        XP[(s + 2) * 68 + lane] = xv.z + pv[v].z;
        XP[(s + 3) * 68 + lane] = xv.w + pv[v].w;
      }
    }
  }
  // no barrier: stage B thread reads row tid>>2, written by its own wave

  // ---- B+C: LayerNorm (4 threads/row, quad shuffle) -> x_norm bf16 in-place
  //      into P1 row bytes 0..127 (cols 0..63). Same-quad read->write, order
  //      pinned by sched_barrier(0). ----
  {
    const int s = tid >> 2, q = tid & 3;
    const float4* pg = (const float4*)(gam + q * 16);
    const float4* pb = (const float4*)(bet + q * 16);
    float4 g0 = pg[0], g1 = pg[1], g2 = pg[2], g3 = pg[3];
    float4 b0v = pb[0], b1 = pb[1], b2 = pb[2], b3 = pb[3];
    float gr[16] = {g0.x, g0.y, g0.z, g0.w, g1.x, g1.y, g1.z, g1.w,
                    g2.x, g2.y, g2.z, g2.w, g3.x, g3.y, g3.z, g3.w};
    float br[16] = {b0v.x, b0v.y, b0v.z, b0v.w, b1.x, b1.y, b1.z, b1.w,
                    b2.x, b2.y, b2.z, b2.w, b3.x, b3.y, b3.z, b3.w};
#pragma unroll
    for (int it = 0; it < 2; it++) {
      const float* XP = (const float*)P1[it];
      const float4* pr = (const float4*)&XP[s * 68 + q * 16];
      float4 x0 = pr[0], x1 = pr[1], x2 = pr[2], x3 = pr[3];
      float xr[16] = {x0.x, x0.y, x0.z, x0.w, x1.x, x1.y, x1.z, x1.w,
                      x2.x, x2.y, x2.z, x2.w, x3.x, x3.y, x3.z, x3.w};
      float sum = 0.f, ss = 0.f;
#pragma unroll
      for (int i = 0; i < 16; i++) { sum += xr[i]; ss = fmaf(xr[i], xr[i], ss); }
      sum += __shfl_xor(sum, 1); ss += __shfl_xor(ss, 1);
      sum += __shfl_xor(sum, 2); ss += __shfl_xor(ss, 2);
      const float mu = sum * 0.015625f;
      const float rs = __builtin_amdgcn_rsqf(ss * 0.015625f - mu * mu + 1e-5f);
      bfrag o0, o1;
#pragma unroll
      for (int i = 0; i < 8; i++) o0[i] = (__bf16)((xr[i] - mu) * rs * gr[i] + br[i]);
#pragma unroll
      for (int i = 0; i < 8; i++) o1[i] = (__bf16)((xr[8 + i] - mu) * rs * gr[8 + i] + br[8 + i]);
      __builtin_amdgcn_sched_barrier(0);   // f32 reads precede in-place bf16 writes
      *(bfrag*)&P1[it][s * 136 + q * 16] = o0;
      *(bfrag*)&P1[it][s * 136 + q * 16 + 8] = o1;
    }
  }
  __syncthreads();   // #1: x_norm visible to all waves

  // ---- D: QKV. XF frags (both items) then Q/K/V with shared weight loads ----
  bfrag XF[2][4][2];
#pragma unroll
  for (int it = 0; it < 2; it++)
#pragma unroll
    for (int st = 0; st < 4; st++) {
      XF[it][st][0] = *(const bfrag*)&P1[it][(st * 16 + m) * 136 + g * 8];
      XF[it][st][1] = *(const bfrag*)&P1[it][(st * 16 + m) * 136 + 32 + g * 8];
    }
  __syncthreads();   // #2: XF loaded everywhere; Q/K may now overwrite x_norm

  uint32_t pk2v[2][4][2];   // v^T packed: [it][st][rr] = bf16x2 of
                            // v[t=st*16+g*4+2rr+{0,1}][vdim=16w+m]
  {
    // Q and K tiles, transposed (A=W rows n, B=XN): wave w -> n-tiles w, w+4
#pragma unroll
    for (int i = 0; i < 2; i++) {
      const int nt = w + 4 * i;                       // 0..7 (Q: 0-3, K: 4-7)
      bfrag AW0 = cvt8(qkvw + (size_t)(nt * 16 + m) * 64 + g * 8);
      bfrag AW1 = cvt8(qkvw + (size_t)(nt * 16 + m) * 64 + 32 + g * 8);
      float4 qb4 = *(const float4*)(qkvb + nt * 16 + g * 4);
#pragma unroll
      for (int it = 0; it < 2; it++)
#pragma unroll
        for (int st = 0; st < 4; st++) {
          f32x4 c = {0.f, 0.f, 0.f, 0.f};
          c = MFMA16(AW0, XF[it][st][0], c);          // C: col=s, rows=n
          c = MFMA16(AW1, XF[it][st][1], c);
          bf4 pk;
          pk[0] = (__bf16)(c[0] + qb4.x); pk[1] = (__bf16)(c[1] + qb4.y);
          pk[2] = (__bf16)(c[2] + qb4.z); pk[3] = (__bf16)(c[3] + qb4.w);
          *(bf4*)&P1[it][(st * 16 + m) * 136 + nt * 16 + g * 4] = pk;
        }
    }
    // V (A=XN rows s, B=W cols n): wave w -> v-dims 16w..16w+15, kept in regs
    {
      const int n = 128 + w * 16 + m;
      bfrag BV0 = cvt8(qkvw + (size_t)n * 64 + g * 8);
      bfrag BV1 = cvt8(qkvw + (size_t)n * 64 + 32 + g * 8);
      const float vb = qkvb[n];
#pragma unroll
      for (int it = 0; it < 2; it++)
#pragma unroll
        for (int st = 0; st < 4; st++) {
          f32x4 c = {0.f, 0.f, 0.f, 0.f};
          c = MFMA16(XF[it][st][0], BV0, c);          // C: col=v-dim, rows=s
          c = MFMA16(XF[it][st][1], BV1, c);
          pk2v[it][st][0] = pack2(c[0] + vb, c[1] + vb);
          pk2v[it][st][1] = pack2(c[2] + vb, c[3] + vb);
        }
    }
  }
  // no barrier: stage E consumes only this wave's Q/K rows (same-wave LDS
  // ordering) and V from registers

  // ---- E: attention, heads h = 2w, 2w+1 (wave-local); S^T = K*Q^T;
  //      P transposed in-register; V A-frags built by shuffle from pk2v ----
  const bfrag ZF = bsplat(0.f);
  const int srcA = m + 32 * (g & 1);    // P-transpose source lanes
  const int srcB = srcA + 16;
  const bool hi = (g >= 2);
#pragma unroll 1
  for (int hl = 0; hl < 2; hl++) {
    const int h = 2 * w + hl;
    bfrag KA[2][4];
    u32x4 VAU[2][2];
    const int vsrcA = ((g & 1) << 5) + 8 * hl + m;   // lane (g'=(g&1)*2, m'=8hl+m)
    const int vsrcB = vsrcA + 16;                    // g'+1
#pragma unroll
    for (int it = 0; it < 2; it++) {
#pragma unroll
      for (int tt = 0; tt < 4; tt++)
        KA[it][tt] = (lane < 16) ? *(const bfrag*)&P1[it][(tt * 16 + m) * 136 + 64 + h * 8] : ZF;
#pragma unroll
      for (int kf = 0; kf < 2; kf++) {
        // consumer (g,m): A row = vdim 8hl+m, k word u covers t=kf*32+g*8+2u+{0,1}
        // producer reg st = 2kf+(g>>1) (pull both, select on hi), rr = u&1
        uint32_t a0 = (uint32_t)__shfl((int)pk2v[it][2 * kf][0], vsrcA);
        uint32_t c0 = (uint32_t)__shfl((int)pk2v[it][2 * kf + 1][0], vsrcA);
        uint32_t a1 = (uint32_t)__shfl((int)pk2v[it][2 * kf][1], vsrcA);
        uint32_t c1 = (uint32_t)__shfl((int)pk2v[it][2 * kf + 1][1], vsrcA);
        uint32_t a2 = (uint32_t)__shfl((int)pk2v[it][2 * kf][0], vsrcB);
        uint32_t c2 = (uint32_t)__shfl((int)pk2v[it][2 * kf + 1][0], vsrcB);
        uint32_t a3 = (uint32_t)__shfl((int)pk2v[it][2 * kf][1], vsrcB);
        uint32_t c3 = (uint32_t)__shfl((int)pk2v[it][2 * kf + 1][1], vsrcB);
        const uint32_t fill = (m == 8) ? 0x3F803F80u : 0u;  // row 8 = ones (sum row)
        u32x4 U;
        U[0] = (m < 8) ? (hi ? c0 : a0) : fill;
        U[1] = (m < 8) ? (hi ? c1 : a1) : fill;
        U[2] = (m < 8) ? (hi ? c2 : a2) : fill;
        U[3] = (m < 8) ? (hi ? c3 : a3) : fill;
        VAU[it][kf] = U;
      }
    }
#pragma unroll
    for (int st = 0; st < 4; st++) {
      // bias chunk shared across items
      float4 bv[4];
#pragma unroll
      for (int tt = 0; tt < 4; tt++)
        bv[tt] = *(const float4*)(biasg + (size_t)(st * 16 + m) * 64 + tt * 16 + g * 4);
#pragma unroll
      for (int it = 0; it < 2; it++) {
        bfrag QB = (lane < 16) ? *(const bfrag*)&P1[it][(st * 16 + m) * 136 + h * 8] : ZF;
        f32x4 sc[4];
#pragma unroll
        for (int tt = 0; tt < 4; tt++) {
          f32x4 z = {0.f, 0.f, 0.f, 0.f};
          sc[tt] = MFMA16(KA[it][tt], QB, z);   // col=s, rows=t (4 consec/lane)
        }
        uint32_t pk[4][2];
#pragma unroll
        for (int tt = 0; tt < 4; tt++) {
          float e0 = __builtin_amdgcn_exp2f(fmaf(bv[tt].x, LN2I, sc[tt][0] * SCL2));
          float e1 = __builtin_amdgcn_exp2f(fmaf(bv[tt].y, LN2I, sc[tt][1] * SCL2));
          float e2 = __builtin_amdgcn_exp2f(fmaf(bv[tt].z, LN2I, sc[tt][2] * SCL2));
          float e3 = __builtin_amdgcn_exp2f(fmaf(bv[tt].w, LN2I, sc[tt][3] * SCL2));
          pk[tt][0] = pack2(e0, e1);
          pk[tt][1] = pack2(e2, e3);
        }
        // in-register transpose -> PV B-frags (lane s holds 8 consecutive t)
        u32x4 U0, U1;
        {
          uint32_t a0 = __shfl((int)pk[0][0], srcA), a1 = __shfl((int)pk[1][0], srcA);
          uint32_t c0 = __shfl((int)pk[0][1], srcA), c1 = __shfl((int)pk[1][1], srcA);
          uint32_t a2 = __shfl((int)pk[0][0], srcB), a3 = __shfl((int)pk[1][0], srcB);
          uint32_t c2 = __shfl((int)pk[0][1], srcB), c3 = __shfl((int)pk[1][1], srcB);
          U0[0] = hi ? a1 : a0; U0[1] = hi ? c1 : c0;
          U0[2] = hi ? a3 : a2; U0[3] = hi ? c3 : c2;
        }
        {
          uint32_t a0 = __shfl((int)pk[2][0], srcA), a1 = __shfl((int)pk[3][0], srcA);
          uint32_t c0 = __shfl((int)pk[2][1], srcA), c1 = __shfl((int)pk[3][1], srcA);
          uint32_t a2 = __shfl((int)pk[2][0], srcB), a3 = __shfl((int)pk[3][0], srcB);
          uint32_t c2 = __shfl((int)pk[2][1], srcB), c3 = __shfl((int)pk[3][1], srcB);
          U1[0] = hi ? a1 : a0; U1[1] = hi ? c1 : c0;
          U1[2] = hi ? a3 : a2; U1[3] = hi ? c3 : c2;
        }
        bfrag PB0 = __builtin_bit_cast(bfrag, U0);
        bfrag PB1 = __builtin_bit_cast(bfrag, U1);
        bfrag VA0 = __builtin_bit_cast(bfrag, VAU[it][0]);
        bfrag VA1 = __builtin_bit_cast(bfrag, VAU[it][1]);
        f32x4 oo = {0.f, 0.f, 0.f, 0.f};
        oo = MFMA16(VA0, PB0, oo);            // O^T: col=s, rows=d; row 8 = sum
        oo = MFMA16(VA1, PB1, oo);
        const float rsum = __builtin_amdgcn_rcpf(__shfl(oo[0], 32 + m));
        bf4 ov;
#pragma unroll
        for (int r = 0; r < 4; r++) ov[r] = (__bf16)(oo[r] * rsum);
        // AO[s][h*8+d] overwrites this head's (already-consumed) K columns
        if (g < 2) *(bf4*)&P1[it][(st * 16 + m) * 136 + 64 + h * 8 + g * 4] = ov;
      }
    }
  }
  __syncthreads();   // #3: AO complete

  // ---- F: O[s][e] = AO * out_w^T + residual; weight/pos loads shared ----
  {
    bfrag A0[2], A1[2];
#pragma unroll
    for (int it = 0; it < 2; it++) {
      A0[it] = *(const bfrag*)&P1[it][(w * 16 + m) * 136 + 64 + g * 8];
      A1[it] = *(const bfrag*)&P1[it][(w * 16 + m) * 136 + 96 + g * 8];
    }
    const int sbase = w * 16 + g * 4;
#pragma unroll
    for (int et = 0; et < 4; et++) {
      const int e = et * 16 + m;
      bfrag BW0 = cvt8(outw + (size_t)e * 64 + g * 8);
      bfrag BW1 = cvt8(outw + (size_t)e * 64 + 32 + g * 8);
      const float ob = outb[e];
      float4 pv = *(const float4*)(posg + (size_t)e * 64 + sbase);
#pragma unroll
      for (int it = 0; it < 2; it++) {
        const size_t xoff = (size_t)(b0 + it) * 4096;
        f32x4 c = {0.f, 0.f, 0.f, 0.f};
        c = MFMA16(A0[it], BW0, c);           // col=e, rows=s (4 consec/lane)
        c = MFMA16(A1[it], BW1, c);
        float4 xv = *(const float4*)(xg + xoff + (size_t)e * 64 + sbase);
        float4 o;
        o.x = c[0] + ob + xv.x + pv.x;
        o.y = c[1] + ob + xv.y + pv.y;
        o.z = c[2] + ob + xv.z + pv.z;
        o.w = c[3] + ob + xv.w + pv.w;
        *(float4*)(outg + xoff + (size_t)e * 64 + sbase) = o;
      }
    }
  }
}

extern "C" void kernel_launch(void* const* d_in, const int* in_sizes, int n_in,
                              void* d_out, int out_size, void* d_ws, size_t ws_size,
                              hipStream_t stream) {
  const float* xg   = (const float*)d_in[0];
  const float* pos  = (const float*)d_in[1];
  const float* gam  = (const float*)d_in[2];
  const float* bet  = (const float*)d_in[3];
  const float* qkvw = (const float*)d_in[4];
  const float* qkvb = (const float*)d_in[5];
  const float* outw = (const float*)d_in[6];
  const float* outb = (const float*)d_in[7];
  const float* cb   = (const float*)d_in[8];
  float* out = (float*)d_out;
  const int B = in_sizes[0] / (64 * 64);   // 4096
  hipLaunchKernelGGL(chess_attn_kernel, dim3(B / 2), dim3(256), 0, stream,
                     xg, pos, gam, bet, qkvw, qkvb, outw, outb, cb, out);
}

// Round 2
// 214.797 us; speedup vs baseline: 1.1711x; 1.1711x over previous
//
#include <hip/hip_runtime.h>
#include <stdint.h>

// ChessMultiStageAttention: B=4096 fused blocks of (pos-add, LN, QKV, 8-head
// attention S=64 D=8 with chess bias, out-proj, residual). f32 I/O, bf16 MFMA
// (16x16x32_bf16) with f32 accum.
//
// Round-7: fix round-6's spill regression (launch_bounds(256,4) pinned arch
// VGPRs to 64 -> ~227 MB/dispatch scratch traffic). Back to (256,3) so the
// allocator is uncapped-in-practice; register DEMAND is pushed <=128 so the
// hardware still fits 4 waves/EU (LDS 34816 -> 4 WG/CU):
//  * Stage D per-item (XF 64->32 regs); weights reloaded per item (L2-hot).
//    One extra barrier (#2b).
//  * Stage E: KA/QB fragments re-read from LDS per st (KA[2][4] cache
//    eliminated, -32 regs). Legal because AO now overwrites the Q columns
//    (consumed before the store within each stripe) instead of K columns, so
//    K columns stay valid for re-reads. Stage F reads AO at cols 0..63.
//
// MFMA layouts (m89-verified):
//   A: lane m=lane&15 holds row m, k=(lane>>4)*8+j (k-contiguous 16B)
//   B: lane holds col n=lane&15, k=(lane>>4)*8+j
//   C/D: col=lane&15, row=(lane>>4)*4+reg
//
// LDS per item (17408 B; x2 = 34816 B -> 4 WG/CU):
//   P1 [64][136] bf16: (A-B) f32 x+pos view [64][68] / (C) x_norm bf16 in-place
//       cols 0..63 / (D) Q cols 0..63, K cols 64..127 / (E) AO overwrites own
//       heads' Q cols (wave-private; Q consumed before store)

typedef __attribute__((ext_vector_type(8))) __bf16 bfrag;
typedef __attribute__((ext_vector_type(4))) __bf16 bf4;
typedef __attribute__((ext_vector_type(4))) float f32x4;
typedef __attribute__((ext_vector_type(4))) uint32_t u32x4;

#define MFMA16(a, b, c) __builtin_amdgcn_mfma_f32_16x16x32_bf16((a), (b), (c), 0, 0, 0)

static __device__ __forceinline__ bfrag bsplat(float v) {
  bfrag z;
#pragma unroll
  for (int i = 0; i < 8; i++) z[i] = (__bf16)v;
  return z;
}

static __device__ __forceinline__ bfrag cvt8(const float* __restrict__ p) {
  float4 a = *(const float4*)p, b = *(const float4*)(p + 4);
  bfrag r;
  r[0] = (__bf16)a.x; r[1] = (__bf16)a.y; r[2] = (__bf16)a.z; r[3] = (__bf16)a.w;
  r[4] = (__bf16)b.x; r[5] = (__bf16)b.y; r[6] = (__bf16)b.z; r[7] = (__bf16)b.w;
  return r;
}

static __device__ __forceinline__ uint32_t pack2(float a, float b) {
  unsigned short ua = __builtin_bit_cast(unsigned short, (__bf16)a);
  unsigned short ub = __builtin_bit_cast(unsigned short, (__bf16)b);
  return (uint32_t)ua | ((uint32_t)ub << 16);
}

__global__ __launch_bounds__(256, 3) void chess_attn_kernel(
    const float* __restrict__ xg,    const float* __restrict__ posg,
    const float* __restrict__ gam,   const float* __restrict__ bet,
    const float* __restrict__ qkvw,  const float* __restrict__ qkvb,
    const float* __restrict__ outw,  const float* __restrict__ outb,
    const float* __restrict__ biasg, float* __restrict__ outg) {
  __shared__ __attribute__((aligned(16))) __bf16 P1[2][64 * 136];  // 2x17408 B

  const int tid = threadIdx.x, lane = tid & 63, w = tid >> 6;
  const int m = lane & 15, g = lane >> 4;
  const int b0 = blockIdx.x * 2;
  const float LN2I = 1.4426950408889634f;            // log2(e)
  const float SCL2 = 0.35355339059327373f * LN2I;    // (1/sqrt(8))*log2(e)

  // ---- A: x + pos -> P1[it] as f32 [64][68]; wave w fills rows 16w..16w+15 ----
  {
    const float4* pp = (const float4*)(posg + (size_t)lane * 64 + w * 16);
    float4 pv[4] = {pp[0], pp[1], pp[2], pp[3]};     // shared across items
#pragma unroll
    for (int it = 0; it < 2; it++) {
      float* XP = (float*)P1[it];
      const float4* px = (const float4*)(xg + ((size_t)(b0 + it) * 64 + lane) * 64 + w * 16);
#pragma unroll
      for (int v = 0; v < 4; v++) {
        float4 xv = px[v];
        const int s = w * 16 + v * 4;
        XP[(s + 0) * 68 + lane] = xv.x + pv[v].x;
        XP[(s + 1) * 68 + lane] = xv.y + pv[v].y;
        XP[(s + 2) * 68 + lane] = xv.z + pv[v].z;
        XP[(s + 3) * 68 + lane] = xv.w + pv[v].w;
      }
    }
  }
  // no barrier: stage B thread reads row tid>>2, written by its own wave

  // ---- B+C: LayerNorm (4 threads/row, quad shuffle) -> x_norm bf16 in-place
  //      into P1 row bytes 0..127 (cols 0..63). Same-quad read->write, order
  //      pinned by sched_barrier(0). ----
  {
    const int s = tid >> 2, q = tid & 3;
    const float4* pg = (const float4*)(gam + q * 16);
    const float4* pb = (const float4*)(bet + q * 16);
    float4 g0 = pg[0], g1 = pg[1], g2 = pg[2], g3 = pg[3];
    float4 b0v = pb[0], b1 = pb[1], b2 = pb[2], b3 = pb[3];
    float gr[16] = {g0.x, g0.y, g0.z, g0.w, g1.x, g1.y, g1.z, g1.w,
                    g2.x, g2.y, g2.z, g2.w, g3.x, g3.y, g3.z, g3.w};
    float br[16] = {b0v.x, b0v.y, b0v.z, b0v.w, b1.x, b1.y, b1.z, b1.w,
                    b2.x, b2.y, b2.z, b2.w, b3.x, b3.y, b3.z, b3.w};
#pragma unroll
    for (int it = 0; it < 2; it++) {
      const float* XP = (const float*)P1[it];
      const float4* pr = (const float4*)&XP[s * 68 + q * 16];
      float4 x0 = pr[0], x1 = pr[1], x2 = pr[2], x3 = pr[3];
      float xr[16] = {x0.x, x0.y, x0.z, x0.w, x1.x, x1.y, x1.z, x1.w,
                      x2.x, x2.y, x2.z, x2.w, x3.x, x3.y, x3.z, x3.w};
      float sum = 0.f, ss = 0.f;
#pragma unroll
      for (int i = 0; i < 16; i++) { sum += xr[i]; ss = fmaf(xr[i], xr[i], ss); }
      sum += __shfl_xor(sum, 1); ss += __shfl_xor(ss, 1);
      sum += __shfl_xor(sum, 2); ss += __shfl_xor(ss, 2);
      const float mu = sum * 0.015625f;
      const float rs = __builtin_amdgcn_rsqf(ss * 0.015625f - mu * mu + 1e-5f);
      bfrag o0, o1;
#pragma unroll
      for (int i = 0; i < 8; i++) o0[i] = (__bf16)((xr[i] - mu) * rs * gr[i] + br[i]);
#pragma unroll
      for (int i = 0; i < 8; i++) o1[i] = (__bf16)((xr[8 + i] - mu) * rs * gr[8 + i] + br[8 + i]);
      __builtin_amdgcn_sched_barrier(0);   // f32 reads precede in-place bf16 writes
      *(bfrag*)&P1[it][s * 136 + q * 16] = o0;
      *(bfrag*)&P1[it][s * 136 + q * 16 + 8] = o1;
    }
  }
  __syncthreads();   // #1: x_norm visible to all waves

  // ---- D: QKV, per-item (halves XF liveness: 32 regs). Weights reloaded per
  //      item from L2-hot qkvw. Barrier per item: all waves must read
  //      x_norm[it] (XF) before Q/K overwrite P1[it] cols 0..127. ----
  uint32_t pk2v[2][4][2];   // v^T packed: [it][st][rr] = bf16x2 of
                            // v[t=st*16+g*4+2rr+{0,1}][vdim=16w+m]
#pragma unroll
  for (int it = 0; it < 2; it++) {
    bfrag XF[4][2];
#pragma unroll
    for (int st = 0; st < 4; st++) {
      XF[st][0] = *(const bfrag*)&P1[it][(st * 16 + m) * 136 + g * 8];
      XF[st][1] = *(const bfrag*)&P1[it][(st * 16 + m) * 136 + 32 + g * 8];
    }
    __syncthreads();   // #2a/#2b: all waves done reading x_norm[it]

    // Q and K tiles, transposed (A=W rows n, B=XN): wave w -> n-tiles w, w+4
#pragma unroll
    for (int i = 0; i < 2; i++) {
      const int nt = w + 4 * i;                       // 0..7 (Q: 0-3, K: 4-7)
      bfrag AW0 = cvt8(qkvw + (size_t)(nt * 16 + m) * 64 + g * 8);
      bfrag AW1 = cvt8(qkvw + (size_t)(nt * 16 + m) * 64 + 32 + g * 8);
      float4 qb4 = *(const float4*)(qkvb + nt * 16 + g * 4);
#pragma unroll
      for (int st = 0; st < 4; st++) {
        f32x4 c = {0.f, 0.f, 0.f, 0.f};
        c = MFMA16(AW0, XF[st][0], c);                // C: col=s, rows=n
        c = MFMA16(AW1, XF[st][1], c);
        bf4 pk;
        pk[0] = (__bf16)(c[0] + qb4.x); pk[1] = (__bf16)(c[1] + qb4.y);
        pk[2] = (__bf16)(c[2] + qb4.z); pk[3] = (__bf16)(c[3] + qb4.w);
        *(bf4*)&P1[it][(st * 16 + m) * 136 + nt * 16 + g * 4] = pk;
      }
    }
    // V (A=XN rows s, B=W cols n): wave w -> v-dims 16w..16w+15, kept in regs
    {
      const int n = 128 + w * 16 + m;
      bfrag BV0 = cvt8(qkvw + (size_t)n * 64 + g * 8);
      bfrag BV1 = cvt8(qkvw + (size_t)n * 64 + 32 + g * 8);
      const float vb = qkvb[n];
#pragma unroll
      for (int st = 0; st < 4; st++) {
        f32x4 c = {0.f, 0.f, 0.f, 0.f};
        c = MFMA16(XF[st][0], BV0, c);                // C: col=v-dim, rows=s
        c = MFMA16(XF[st][1], BV1, c);
        pk2v[it][st][0] = pack2(c[0] + vb, c[1] + vb);
        pk2v[it][st][1] = pack2(c[2] + vb, c[3] + vb);
      }
    }
  }
  // no barrier: stage E consumes only this wave's Q/K columns (same-wave LDS
  // ordering) and V from registers

  // ---- E: attention, heads h = 2w, 2w+1 (wave-local); S^T = K*Q^T;
  //      P transposed in-register; V A-frags built by shuffle from pk2v.
  //      KA/QB re-read from LDS per stripe (no KA register cache); AO
  //      overwrites Q cols (consumed before store), K cols stay valid. ----
  const bfrag ZF = bsplat(0.f);
  const int srcA = m + 32 * (g & 1);    // P-transpose source lanes
  const int srcB = srcA + 16;
  const bool hi = (g >= 2);
#pragma unroll 1
  for (int hl = 0; hl < 2; hl++) {
    const int h = 2 * w + hl;
    u32x4 VA[2][2];
    const int vsrcA = ((g & 1) << 5) + 8 * hl + m;   // lane (g'=(g&1)*2, m'=8hl+m)
    const int vsrcB = vsrcA + 16;                    // g'+1
#pragma unroll
    for (int it = 0; it < 2; it++)
#pragma unroll
      for (int kf = 0; kf < 2; kf++) {
        // consumer (g,m): A row = vdim 8hl+m, k word u covers t=kf*32+g*8+2u+{0,1}
        // producer reg st = 2kf+(g>>1) (pull both, select on hi), rr = u&1
        uint32_t a0 = (uint32_t)__shfl((int)pk2v[it][2 * kf][0], vsrcA);
        uint32_t c0 = (uint32_t)__shfl((int)pk2v[it][2 * kf + 1][0], vsrcA);
        uint32_t a1 = (uint32_t)__shfl((int)pk2v[it][2 * kf][1], vsrcA);
        uint32_t c1 = (uint32_t)__shfl((int)pk2v[it][2 * kf + 1][1], vsrcA);
        uint32_t a2 = (uint32_t)__shfl((int)pk2v[it][2 * kf][0], vsrcB);
        uint32_t c2 = (uint32_t)__shfl((int)pk2v[it][2 * kf + 1][0], vsrcB);
        uint32_t a3 = (uint32_t)__shfl((int)pk2v[it][2 * kf][1], vsrcB);
        uint32_t c3 = (uint32_t)__shfl((int)pk2v[it][2 * kf + 1][1], vsrcB);
        const uint32_t fill = (m == 8) ? 0x3F803F80u : 0u;  // row 8 = ones (sum row)
        u32x4 U;
        U[0] = (m < 8) ? (hi ? c0 : a0) : fill;
        U[1] = (m < 8) ? (hi ? c1 : a1) : fill;
        U[2] = (m < 8) ? (hi ? c2 : a2) : fill;
        U[3] = (m < 8) ? (hi ? c3 : a3) : fill;
        VA[it][kf] = U;
      }
#pragma unroll
    for (int st = 0; st < 4; st++) {
      // bias chunk shared across items
      float4 bv[4];
#pragma unroll
      for (int tt = 0; tt < 4; tt++)
        bv[tt] = *(const float4*)(biasg + (size_t)(st * 16 + m) * 64 + tt * 16 + g * 4);
#pragma unroll
      for (int it = 0; it < 2; it++) {
        const __bf16* Pit = P1[it];
        bfrag QB = (lane < 16) ? *(const bfrag*)&Pit[(st * 16 + m) * 136 + h * 8] : ZF;
        f32x4 sc[4];
#pragma unroll
        for (int tt = 0; tt < 4; tt++) {
          bfrag KA = (lane < 16) ? *(const bfrag*)&Pit[(tt * 16 + m) * 136 + 64 + h * 8] : ZF;
          f32x4 z = {0.f, 0.f, 0.f, 0.f};
          sc[tt] = MFMA16(KA, QB, z);   // col=s, rows=t (4 consec/lane)
        }
        uint32_t pk[4][2];
#pragma unroll
        for (int tt = 0; tt < 4; tt++) {
          float e0 = __builtin_amdgcn_exp2f(fmaf(bv[tt].x, LN2I, sc[tt][0] * SCL2));
          float e1 = __builtin_amdgcn_exp2f(fmaf(bv[tt].y, LN2I, sc[tt][1] * SCL2));
          float e2 = __builtin_amdgcn_exp2f(fmaf(bv[tt].z, LN2I, sc[tt][2] * SCL2));
          float e3 = __builtin_amdgcn_exp2f(fmaf(bv[tt].w, LN2I, sc[tt][3] * SCL2));
          pk[tt][0] = pack2(e0, e1);
          pk[tt][1] = pack2(e2, e3);
        }
        // in-register transpose -> PV B-frags (lane s holds 8 consecutive t)
        u32x4 U0, U1;
        {
          uint32_t a0 = __shfl((int)pk[0][0], srcA), a1 = __shfl((int)pk[1][0], srcA);
          uint32_t c0 = __shfl((int)pk[0][1], srcA), c1 = __shfl((int)pk[1][1], srcA);
          uint32_t a2 = __shfl((int)pk[0][0], srcB), a3 = __shfl((int)pk[1][0], srcB);
          uint32_t c2 = __shfl((int)pk[0][1], srcB), c3 = __shfl((int)pk[1][1], srcB);
          U0[0] = hi ? a1 : a0; U0[1] = hi ? c1 : c0;
          U0[2] = hi ? a3 : a2; U0[3] = hi ? c3 : c2;
        }
        {
          uint32_t a0 = __shfl((int)pk[2][0], srcA), a1 = __shfl((int)pk[3][0], srcA);
          uint32_t c0 = __shfl((int)pk[2][1], srcA), c1 = __shfl((int)pk[3][1], srcA);
          uint32_t a2 = __shfl((int)pk[2][0], srcB), a3 = __shfl((int)pk[3][0], srcB);
          uint32_t c2 = __shfl((int)pk[2][1], srcB), c3 = __shfl((int)pk[3][1], srcB);
          U1[0] = hi ? a1 : a0; U1[1] = hi ? c1 : c0;
          U1[2] = hi ? a3 : a2; U1[3] = hi ? c3 : c2;
        }
        bfrag PB0 = __builtin_bit_cast(bfrag, U0);
        bfrag PB1 = __builtin_bit_cast(bfrag, U1);
        bfrag VA0 = __builtin_bit_cast(bfrag, VA[it][0]);
        bfrag VA1 = __builtin_bit_cast(bfrag, VA[it][1]);
        f32x4 oo = {0.f, 0.f, 0.f, 0.f};
        oo = MFMA16(VA0, PB0, oo);            // O^T: col=s, rows=d; row 8 = sum
        oo = MFMA16(VA1, PB1, oo);
        const float rsum = __builtin_amdgcn_rcpf(__shfl(oo[0], 32 + m));
        bf4 ov;
#pragma unroll
        for (int r = 0; r < 4; r++) ov[r] = (__bf16)(oo[r] * rsum);
        // AO[s][h*8+d] overwrites this head's (already-consumed) Q columns
        if (g < 2) *(bf4*)&P1[it][(st * 16 + m) * 136 + h * 8 + g * 4] = ov;
      }
    }
  }
  __syncthreads();   // #3: AO complete

  // ---- F: O[s][e] = AO * out_w^T + residual; AO lives in cols 0..63 ----
  {
    bfrag A0[2], A1[2];
#pragma unroll
    for (int it = 0; it < 2; it++) {
      A0[it] = *(const bfrag*)&P1[it][(w * 16 + m) * 136 + g * 8];
      A1[it] = *(const bfrag*)&P1[it][(w * 16 + m) * 136 + 32 + g * 8];
    }
    const int sbase = w * 16 + g * 4;
#pragma unroll
    for (int et = 0; et < 4; et++) {
      const int e = et * 16 + m;
      bfrag BW0 = cvt8(outw + (size_t)e * 64 + g * 8);
      bfrag BW1 = cvt8(outw + (size_t)e * 64 + 32 + g * 8);
      const float ob = outb[e];
      float4 pv = *(const float4*)(posg + (size_t)e * 64 + sbase);
#pragma unroll
      for (int it = 0; it < 2; it++) {
        const size_t xoff = (size_t)(b0 + it) * 4096;
        f32x4 c = {0.f, 0.f, 0.f, 0.f};
        c = MFMA16(A0[it], BW0, c);           // col=e, rows=s (4 consec/lane)
        c = MFMA16(A1[it], BW1, c);
        float4 xv = *(const float4*)(xg + xoff + (size_t)e * 64 + sbase);
        float4 o;
        o.x = c[0] + ob + xv.x + pv.x;
        o.y = c[1] + ob + xv.y + pv.y;
        o.z = c[2] + ob + xv.z + pv.z;
        o.w = c[3] + ob + xv.w + pv.w;
        *(float4*)(outg + xoff + (size_t)e * 64 + sbase) = o;
      }
    }
  }
}

extern "C" void kernel_launch(void* const* d_in, const int* in_sizes, int n_in,
                              void* d_out, int out_size, void* d_ws, size_t ws_size,
                              hipStream_t stream) {
  const float* xg   = (const float*)d_in[0];
  const float* pos  = (const float*)d_in[1];
  const float* gam  = (const float*)d_in[2];
  const float* bet  = (const float*)d_in[3];
  const float* qkvw = (const float*)d_in[4];
  const float* qkvb = (const float*)d_in[5];
  const float* outw = (const float*)d_in[6];
  const float* outb = (const float*)d_in[7];
  const float* cb   = (const float*)d_in[8];
  float* out = (float*)d_out;
  const int B = in_sizes[0] / (64 * 64);   // 4096
  hipLaunchKernelGGL(chess_attn_kernel, dim3(B / 2), dim3(256), 0, stream,
                     xg, pos, gam, bet, qkvw, qkvb, outw, outb, cb, out);
}

// Round 3
// 190.792 us; speedup vs baseline: 1.3185x; 1.1258x over previous
//
#include <hip/hip_runtime.h>
#include <stdint.h>

// ChessMultiStageAttention: B=4096 fused blocks of (pos-add, LN, QKV, 8-head
// attention S=64 D=8 with chess bias, out-proj, residual). f32 I/O, bf16 MFMA
// (16x16x32_bf16) with f32 accum.
//
// Round-8: revert to the round-5 structure (98 us/dispatch champion; the
// LDS-shrink path of rounds 6-7 proved occupancy is NOT LDS-limited) and cut
// stage-E VALU + dep-chain length:
//  * chess bias folded into the score MFMA accumulator init (C-fragment
//    layout == bias tile layout), pre-scaled by log2(e): the per-element
//    fmaf(bias, LN2I, ...) is gone.
//  * softmax scale (1/sqrt(8)*log2e) folded into Q at the stage-D store:
//    stage E computes exp2(sc) directly (per-element mul gone).
//  * P-transpose via wave-private LDS bounce instead of 16 bpermute + 8
//    cndmask + packing per (hl,st,it): exp results stored as bf4
//    (4x ds_write_b64), PV B-frags read back as 2x ds_read_b128. Scratch
//    overlays the wave's OWN already-consumed v^T rows in P2 (rows 8w..8w+7
//    of both items; VA fragments are register-hoisted before first use), so
//    no extra barrier and no extra LDS.
//
// MFMA layouts (m89-verified):
//   A: lane m=lane&15 holds row m, k=(lane>>4)*8+j (k-contiguous 16B)
//   B: lane holds col n=lane&15, k=(lane>>4)*8+j
//   C/D: col=lane&15, row=(lane>>4)*4+reg
//
// LDS per item (26624 B; x2 = 53248 B -> 3 WG/CU):
//   P1 [64][136] bf16: (A-B) f32 x+pos view [64][68] / (D) Q cols 0..63
//       (pre-scaled), K cols 64..127 / (E) AO overwrites own head's K cols
//   P2 [64][72]  bf16: (C) x_norm -> XF regs / (D-E) v^T [(h,d)][t] /
//       (E) rows 8w..8w+7 of both items double as wave-w P-scratch

typedef __attribute__((ext_vector_type(8))) __bf16 bfrag;
typedef __attribute__((ext_vector_type(4))) __bf16 bf4;
typedef __attribute__((ext_vector_type(4))) float f32x4;

#define MFMA16(a, b, c) __builtin_amdgcn_mfma_f32_16x16x32_bf16((a), (b), (c), 0, 0, 0)

static __device__ __forceinline__ bfrag bsplat(float v) {
  bfrag z;
#pragma unroll
  for (int i = 0; i < 8; i++) z[i] = (__bf16)v;
  return z;
}

static __device__ __forceinline__ bfrag cvt8(const float* __restrict__ p) {
  float4 a = *(const float4*)p, b = *(const float4*)(p + 4);
  bfrag r;
  r[0] = (__bf16)a.x; r[1] = (__bf16)a.y; r[2] = (__bf16)a.z; r[3] = (__bf16)a.w;
  r[4] = (__bf16)b.x; r[5] = (__bf16)b.y; r[6] = (__bf16)b.z; r[7] = (__bf16)b.w;
  return r;
}

__global__ __launch_bounds__(256, 3) void chess_attn_kernel(
    const float* __restrict__ xg,    const float* __restrict__ posg,
    const float* __restrict__ gam,   const float* __restrict__ bet,
    const float* __restrict__ qkvw,  const float* __restrict__ qkvb,
    const float* __restrict__ outw,  const float* __restrict__ outb,
    const float* __restrict__ biasg, float* __restrict__ outg) {
  __shared__ __attribute__((aligned(16))) __bf16 P1[2][64 * 136];  // 2x17408 B
  __shared__ __attribute__((aligned(16))) __bf16 P2[2][64 * 72];   // 2x 9216 B

  const int tid = threadIdx.x, lane = tid & 63, w = tid >> 6;
  const int m = lane & 15, g = lane >> 4;
  const int b0 = blockIdx.x * 2;
  const float LN2I = 1.4426950408889634f;                       // log2(e)
  const float SCL2 = 0.35355339059327373f * 1.4426950408889634f; // (1/sqrt8)*log2e

  // ---- A: x + pos -> P1[it] as f32 [64][68]; wave w fills rows 16w..16w+15 ----
  {
    const float4* pp = (const float4*)(posg + (size_t)lane * 64 + w * 16);
    float4 pv[4] = {pp[0], pp[1], pp[2], pp[3]};     // shared across items
#pragma unroll
    for (int it = 0; it < 2; it++) {
      float* XP = (float*)P1[it];
      const float4* px = (const float4*)(xg + ((size_t)(b0 + it) * 64 + lane) * 64 + w * 16);
#pragma unroll
      for (int v = 0; v < 4; v++) {
        float4 xv = px[v];
        const int s = w * 16 + v * 4;
        XP[(s + 0) * 68 + lane] = xv.x + pv[v].x;
        XP[(s + 1) * 68 + lane] = xv.y + pv[v].y;
        XP[(s + 2) * 68 + lane] = xv.z + pv[v].z;
        XP[(s + 3) * 68 + lane] = xv.w + pv[v].w;
      }
    }
  }
  // no barrier: stage B thread reads row tid>>2, written by its own wave

  // ---- B+C: LayerNorm (4 threads/row, quad shuffle) -> XN in P2[it] ----
  {
    const int s = tid >> 2, q = tid & 3;
    const float4* pg = (const float4*)(gam + q * 16);
    const float4* pb = (const float4*)(bet + q * 16);
    float4 g0 = pg[0], g1 = pg[1], g2 = pg[2], g3 = pg[3];
    float4 b0v = pb[0], b1 = pb[1], b2 = pb[2], b3 = pb[3];
    float gr[16] = {g0.x, g0.y, g0.z, g0.w, g1.x, g1.y, g1.z, g1.w,
                    g2.x, g2.y, g2.z, g2.w, g3.x, g3.y, g3.z, g3.w};
    float br[16] = {b0v.x, b0v.y, b0v.z, b0v.w, b1.x, b1.y, b1.z, b1.w,
                    b2.x, b2.y, b2.z, b2.w, b3.x, b3.y, b3.z, b3.w};
#pragma unroll
    for (int it = 0; it < 2; it++) {
      const float* XP = (const float*)P1[it];
      const float4* pr = (const float4*)&XP[s * 68 + q * 16];
      float4 x0 = pr[0], x1 = pr[1], x2 = pr[2], x3 = pr[3];
      float xr[16] = {x0.x, x0.y, x0.z, x0.w, x1.x, x1.y, x1.z, x1.w,
                      x2.x, x2.y, x2.z, x2.w, x3.x, x3.y, x3.z, x3.w};
      float sum = 0.f, ss = 0.f;
#pragma unroll
      for (int i = 0; i < 16; i++) { sum += xr[i]; ss = fmaf(xr[i], xr[i], ss); }
      sum += __shfl_xor(sum, 1); ss += __shfl_xor(ss, 1);
      sum += __shfl_xor(sum, 2); ss += __shfl_xor(ss, 2);
      const float mu = sum * 0.015625f;
      const float rs = __builtin_amdgcn_rsqf(ss * 0.015625f - mu * mu + 1e-5f);
      bfrag o0, o1;
#pragma unroll
      for (int i = 0; i < 8; i++) o0[i] = (__bf16)((xr[i] - mu) * rs * gr[i] + br[i]);
#pragma unroll
      for (int i = 0; i < 8; i++) o1[i] = (__bf16)((xr[8 + i] - mu) * rs * gr[8 + i] + br[8 + i]);
      *(bfrag*)&P2[it][s * 72 + q * 16] = o0;
      *(bfrag*)&P2[it][s * 72 + q * 16 + 8] = o1;
    }
  }
  __syncthreads();   // #1: XN visible to all waves

  // ---- D: QKV. XF frags (both items) then Q/K/V with shared weight loads ----
  bfrag XF[2][4][2];
#pragma unroll
  for (int it = 0; it < 2; it++)
#pragma unroll
    for (int st = 0; st < 4; st++) {
      XF[it][st][0] = *(const bfrag*)&P2[it][(st * 16 + m) * 72 + g * 8];
      XF[it][st][1] = *(const bfrag*)&P2[it][(st * 16 + m) * 72 + 32 + g * 8];
    }
  __syncthreads();   // #2: XF loaded everywhere; V may now overwrite P2

  {
    // Q and K tiles, transposed (A=W rows n, B=XN): wave w -> n-tiles w, w+4
    // Q (i==0) pre-scaled by SCL2 so stage E is exp2(sc) directly.
#pragma unroll
    for (int i = 0; i < 2; i++) {
      const int nt = w + 4 * i;                       // 0..7 (Q: 0-3, K: 4-7)
      bfrag AW0 = cvt8(qkvw + (size_t)(nt * 16 + m) * 64 + g * 8);
      bfrag AW1 = cvt8(qkvw + (size_t)(nt * 16 + m) * 64 + 32 + g * 8);
      float4 qb4 = *(const float4*)(qkvb + nt * 16 + g * 4);
      const float qs = (i == 0) ? SCL2 : 1.0f;
      const float qbx = qb4.x * qs, qby = qb4.y * qs;
      const float qbz = qb4.z * qs, qbw = qb4.w * qs;
#pragma unroll
      for (int it = 0; it < 2; it++)
#pragma unroll
        for (int st = 0; st < 4; st++) {
          f32x4 c = {0.f, 0.f, 0.f, 0.f};
          c = MFMA16(AW0, XF[it][st][0], c);          // C: col=s, rows=n
          c = MFMA16(AW1, XF[it][st][1], c);
          bf4 pk;
          pk[0] = (__bf16)fmaf(c[0], qs, qbx); pk[1] = (__bf16)fmaf(c[1], qs, qby);
          pk[2] = (__bf16)fmaf(c[2], qs, qbz); pk[3] = (__bf16)fmaf(c[3], qs, qbw);
          *(bf4*)&P1[it][(st * 16 + m) * 136 + nt * 16 + g * 4] = pk;
        }
    }
    // V (A=XN rows s, B=W cols n): wave w -> v^T rows 16w..16w+15
    {
      const int n = 128 + w * 16 + m;
      bfrag BV0 = cvt8(qkvw + (size_t)n * 64 + g * 8);
      bfrag BV1 = cvt8(qkvw + (size_t)n * 64 + 32 + g * 8);
      const float vb = qkvb[n];
#pragma unroll
      for (int it = 0; it < 2; it++)
#pragma unroll
        for (int st = 0; st < 4; st++) {
          f32x4 c = {0.f, 0.f, 0.f, 0.f};
          c = MFMA16(XF[it][st][0], BV0, c);          // C: col=v-row, rows=s
          c = MFMA16(XF[it][st][1], BV1, c);
          bf4 pk;
#pragma unroll
          for (int r = 0; r < 4; r++) pk[r] = (__bf16)(c[r] + vb);
          *(bf4*)&P2[it][(w * 16 + m) * 72 + st * 16 + g * 4] = pk;
        }
    }
  }
  __syncthreads();   // #3: Q/K/V complete

  // ---- E: attention, heads h = w, w+4; S^T = K*Q^T with bias*log2e as the
  //      accumulator init; P -> PV B-frags via wave-private LDS bounce in P2
  //      (rows 8w..8w+7 of both items = this wave's consumed v^T rows). ----
  const bfrag ZF  = bsplat(0.f);
  const bfrag ONE = bsplat(1.f);
  __bf16* PS = &P2[0][0];
  // P-scratch row for s-local = m: s'<8 -> P2[0] row 8w+s', s'>=8 -> P2[1]
  // row 8w+(s'-8). Bank-base = 4*(m&7): reads/writes land at the LDS BW floor.
  const int rowoff = (8 * w + (m & 7)) * 72 + (m >> 3) * 4608;
#pragma unroll 1
  for (int hl = 0; hl < 2; hl++) {
    const int h = w + hl * 4;
    bfrag KA[2][4], VA[2][2];
#pragma unroll
    for (int it = 0; it < 2; it++) {
#pragma unroll
      for (int tt = 0; tt < 4; tt++)
        KA[it][tt] = (lane < 16) ? *(const bfrag*)&P1[it][(tt * 16 + m) * 136 + 64 + h * 8] : ZF;
#pragma unroll
      for (int kf = 0; kf < 2; kf++)
        VA[it][kf] = (m < 8) ? *(const bfrag*)&P2[it][(h * 8 + m) * 72 + kf * 32 + g * 8]
                             : ((m == 8) ? ONE : ZF);
    }
#pragma unroll
    for (int st = 0; st < 4; st++) {
      // bias tile in C-fragment layout, pre-scaled by log2(e); shared across it
      f32x4 binit[4];
#pragma unroll
      for (int tt = 0; tt < 4; tt++) {
        float4 bv = *(const float4*)(biasg + (size_t)(st * 16 + m) * 64 + tt * 16 + g * 4);
        binit[tt][0] = bv.x * LN2I; binit[tt][1] = bv.y * LN2I;
        binit[tt][2] = bv.z * LN2I; binit[tt][3] = bv.w * LN2I;
      }
#pragma unroll
      for (int it = 0; it < 2; it++) {
        bfrag QB = (lane < 16) ? *(const bfrag*)&P1[it][(st * 16 + m) * 136 + h * 8] : ZF;
        // scores + exp2 + bf16, stored to P-scratch (producer: s'=m, t=tt*16+g*4)
#pragma unroll
        for (int tt = 0; tt < 4; tt++) {
          f32x4 sc = MFMA16(KA[it][tt], QB, binit[tt]);  // col=s, rows=t
          bf4 pr;
          pr[0] = (__bf16)__builtin_amdgcn_exp2f(sc[0]);
          pr[1] = (__bf16)__builtin_amdgcn_exp2f(sc[1]);
          pr[2] = (__bf16)__builtin_amdgcn_exp2f(sc[2]);
          pr[3] = (__bf16)__builtin_amdgcn_exp2f(sc[3]);
          *(bf4*)&PS[rowoff + tt * 16 + g * 4] = pr;
        }
        // consumer: PV B-frags, lane (n=s'=m, kg=g) reads t = kf*32+g*8..+7
        bfrag PB0 = *(const bfrag*)&PS[rowoff + g * 8];
        bfrag PB1 = *(const bfrag*)&PS[rowoff + 32 + g * 8];
        f32x4 oo = {0.f, 0.f, 0.f, 0.f};
        oo = MFMA16(VA[it][0], PB0, oo);      // O^T: col=s, rows=d; row 8 = sum
        oo = MFMA16(VA[it][1], PB1, oo);
        const float rsum = __builtin_amdgcn_rcpf(__shfl(oo[0], 32 + m));
        bf4 ov;
#pragma unroll
        for (int r = 0; r < 4; r++) ov[r] = (__bf16)(oo[r] * rsum);
        // AO[s][h*8+d] overwrites this head's (already-consumed) K columns
        if (g < 2) *(bf4*)&P1[it][(st * 16 + m) * 136 + 64 + h * 8 + g * 4] = ov;
      }
    }
  }
  __syncthreads();   // #4: AO complete

  // ---- F: O[s][e] = AO * out_w^T + residual; weight/pos loads shared ----
  {
    bfrag A0[2], A1[2];
#pragma unroll
    for (int it = 0; it < 2; it++) {
      A0[it] = *(const bfrag*)&P1[it][(w * 16 + m) * 136 + 64 + g * 8];
      A1[it] = *(const bfrag*)&P1[it][(w * 16 + m) * 136 + 96 + g * 8];
    }
    const int sbase = w * 16 + g * 4;
#pragma unroll
    for (int et = 0; et < 4; et++) {
      const int e = et * 16 + m;
      bfrag BW0 = cvt8(outw + (size_t)e * 64 + g * 8);
      bfrag BW1 = cvt8(outw + (size_t)e * 64 + 32 + g * 8);
      const float ob = outb[e];
      float4 pv = *(const float4*)(posg + (size_t)e * 64 + sbase);
#pragma unroll
      for (int it = 0; it < 2; it++) {
        const size_t xoff = (size_t)(b0 + it) * 4096;
        f32x4 c = {0.f, 0.f, 0.f, 0.f};
        c = MFMA16(A0[it], BW0, c);           // col=e, rows=s (4 consec/lane)
        c = MFMA16(A1[it], BW1, c);
        float4 xv = *(const float4*)(xg + xoff + (size_t)e * 64 + sbase);
        float4 o;
        o.x = c[0] + ob + xv.x + pv.x;
        o.y = c[1] + ob + xv.y + pv.y;
        o.z = c[2] + ob + xv.z + pv.z;
        o.w = c[3] + ob + xv.w + pv.w;
        *(float4*)(outg + xoff + (size_t)e * 64 + sbase) = o;
      }
    }
  }
}

extern "C" void kernel_launch(void* const* d_in, const int* in_sizes, int n_in,
                              void* d_out, int out_size, void* d_ws, size_t ws_size,
                              hipStream_t stream) {
  const float* xg   = (const float*)d_in[0];
  const float* pos  = (const float*)d_in[1];
  const float* gam  = (const float*)d_in[2];
  const float* bet  = (const float*)d_in[3];
  const float* qkvw = (const float*)d_in[4];
  const float* qkvb = (const float*)d_in[5];
  const float* outw = (const float*)d_in[6];
  const float* outb = (const float*)d_in[7];
  const float* cb   = (const float*)d_in[8];
  float* out = (float*)d_out;
  const int B = in_sizes[0] / (64 * 64);   // 4096
  hipLaunchKernelGGL(chess_attn_kernel, dim3(B / 2), dim3(256), 0, stream,
                     xg, pos, gam, bet, qkvw, qkvb, outw, outb, cb, out);
}